// Round 8
// baseline (509.961 us; speedup 1.0000x reference)
//
#include <hip/hip_runtime.h>
#include <math.h>

typedef short s16x8 __attribute__((ext_vector_type(8)));
typedef float f32x16 __attribute__((ext_vector_type(16)));
typedef float f32x2 __attribute__((ext_vector_type(2)));
typedef unsigned u32x4 __attribute__((ext_vector_type(4)));

#define N_NODES 100000
#define N_EDGESC 1000000
#define NODE_DIM 64
#define NG 31250        // 1e6 / 32 edges per group (exact)
#define GPB 16          // groups per block (4 waves x 2 groups x 2 passes)
#define NPASS 2

// round-to-nearest-even f32 -> bf16 bits (prep only)
__device__ __forceinline__ unsigned short f2bf(float f){
  unsigned u = __float_as_uint(f);
  u += 0x7fffu + ((u >> 16) & 1u);
  return (unsigned short)(u >> 16);
}

// pack two f32 -> one u32 of 2x bf16 (RNE), single HW op
__device__ __forceinline__ unsigned cvt_pk_bf16(float lo, float hi){
  unsigned r;
  asm("v_cvt_pk_bf16_f32 %0, %1, %2" : "=v"(r) : "v"(lo), "v"(hi));
  return r;
}

// 2x fp8(e4m3, low 16 bits of src) -> 2x f32 (HW)
__device__ __forceinline__ f32x2 cvt_pk_f32_fp8(unsigned w){
  f32x2 r;
  asm("v_cvt_pk_f32_fp8 %0, %1" : "=v"(r) : "v"(w));
  return r;
}

// dequant one 8-byte fp8 pair (dlo,dhi) -> bf16 MFMA fragment
__device__ __forceinline__ s16x8 deq_frag(unsigned dlo, unsigned dhi){
  const f32x2 f01 = cvt_pk_f32_fp8(dlo);
  const f32x2 f23 = cvt_pk_f32_fp8(dlo >> 16);
  const f32x2 f45 = cvt_pk_f32_fp8(dhi);
  const f32x2 f67 = cvt_pk_f32_fp8(dhi >> 16);
  u32x4 r;
  r[0] = cvt_pk_bf16(f01[0], f01[1]);
  r[1] = cvt_pk_bf16(f23[0], f23[1]);
  r[2] = cvt_pk_bf16(f45[0], f45[1]);
  r[3] = cvt_pk_bf16(f67[0], f67[1]);
  return __builtin_bit_cast(s16x8, r);
}

// Prep (unchanged from R6): blocks [0,2048) cast node table f32 -> fp8 e4m3
// (6.4 MB, 64B rows = one cache line).  Blocks [2048,2176) pack W1^T/W2^T
// into 32x32x16 A-fragment order; W1's k-rows permuted so a lane's gathered
// 32B half-row is contiguous (feature = half*64 + h*32 + (kf&3)*8 + j).
__global__ void prep_kernel(const float* __restrict__ node,
                            const float* __restrict__ w1,
                            const float* __restrict__ w2,
                            unsigned* __restrict__ nodef,   // fp8, 4 per u32
                            unsigned short* __restrict__ wf){
  const int b = blockIdx.x;
  if (b < 2048){
    int i = b * 256 + threadIdx.x;
    const int n4 = N_NODES * NODE_DIM / 4;
    const int stride = 2048 * 256;
    for (; i < n4; i += stride){
      const float4 v = reinterpret_cast<const float4*>(node)[i];
      unsigned lo = 0, hi = 0;
      asm("v_cvt_pk_fp8_f32 %0, %1, %2" : "+v"(lo) : "v"(v.x), "v"(v.y));
      asm("v_cvt_pk_fp8_f32 %0, %1, %2" : "+v"(hi) : "v"(v.z), "v"(v.w));
      nodef[i] = (lo & 0xffffu) | (hi << 16);
    }
  } else {
    const int i = (b - 2048) * 256 + threadIdx.x;   // 0..32767
    const int ii = i & 16383;
    const int f = ii >> 9, rem = ii & 511, l = rem >> 3, j = rem & 7;
    const int kf = f >> 2, nt = f & 3;
    const int h = l >> 5, n = nt * 32 + (l & 31);
    if (i < 16384){
      const int feat = (kf >> 2) * 64 + h * 32 + (kf & 3) * 8 + j;  // permuted
      wf[i] = f2bf(w1[feat * 128 + n]);
    } else {
      const int k = kf * 16 + h * 8 + j;                            // plain
      wf[i] = f2bf(w2[k * 128 + n]);
    }
  }
}

__device__ __forceinline__ void gather_fp8(const unsigned char* __restrict__ nodef,
                                           int is, int id, int h, u32x4 (&r)[4]){
  const unsigned char* s = nodef + (size_t)is * 64 + h * 32;
  const unsigned char* d = nodef + (size_t)id * 64 + h * 32;
  r[0] = *reinterpret_cast<const u32x4*>(s);
  r[1] = *reinterpret_cast<const u32x4*>(s + 16);
  r[2] = *reinterpret_cast<const u32x4*>(d);
  r[3] = *reinterpret_cast<const u32x4*>(d + 16);
}

// One 2-group pass.  If PF: issue next pass's idx loads at the top (latency
// hides under L1) and its 8 fp8 gathers right after the L1 MFMA loop (where
// rA/rB die) so they complete under crossover+L2+L3.
template<bool PF>
__device__ __forceinline__ void do_pass(
    const unsigned short* wlds, int lane, int h, int er,
    u32x4 (&rA)[4], u32x4 (&rB)[4], long g0, long g1, bool v0, bool v1,
    const unsigned char* __restrict__ nodef, const int* __restrict__ eidx,
    long gn0, long gn1, u32x4 (&rAn)[4], u32x4 (&rBn)[4],
    const float* __restrict__ b1, const float* __restrict__ b2,
    const float* __restrict__ w3, float bias3, float* __restrict__ out)
{
  // ---- prefetch next pass's edge indices (coalesced, cheap)
  int isAn = 0, idAn = 0, isBn = 0, idBn = 0;
  if (PF){
    const long ga = (gn0 < NG) ? gn0 : 0;
    const long gb = (gn1 < NG) ? gn1 : 0;
    isAn = eidx[ga * 32 + er];
    idAn = eidx[N_EDGESC + ga * 32 + er];
    isBn = eidx[gb * 32 + er];
    idBn = eidx[N_EDGESC + gb * 32 + er];
  }

  f32x16 acc[2][4];
  #pragma unroll
  for (int gi = 0; gi < 2; ++gi)
    #pragma unroll
    for (int nt = 0; nt < 4; ++nt)
      #pragma unroll
      for (int r = 0; r < 16; ++r) acc[gi][nt][r] = 0.f;

  // ---- layer 1: dequant frag once per group, share A-read across groups
  #pragma unroll
  for (int kf = 0; kf < 8; ++kf){
    const s16x8 fA = deq_frag(rA[kf >> 1][(kf & 1) * 2], rA[kf >> 1][(kf & 1) * 2 + 1]);
    const s16x8 fB = deq_frag(rB[kf >> 1][(kf & 1) * 2], rB[kf >> 1][(kf & 1) * 2 + 1]);
    #pragma unroll
    for (int nt = 0; nt < 4; ++nt){
      const s16x8 a = *reinterpret_cast<const s16x8*>(
          (const char*)wlds + (kf * 4 + nt) * 1024 + lane * 16);
      acc[0][nt] = __builtin_amdgcn_mfma_f32_32x32x16_bf16(a, fA, acc[0][nt], 0, 0, 0);
      acc[1][nt] = __builtin_amdgcn_mfma_f32_32x32x16_bf16(a, fB, acc[1][nt], 0, 0, 0);
    }
  }

  // ---- rA/rB now dead: issue next pass's gathers (complete under L2/L3)
  if (PF){
    gather_fp8(nodef, isAn, idAn, h, rAn);
    gather_fp8(nodef, isBn, idBn, h, rBn);
  }

  // ---- bias + relu in place (both groups)
  #pragma unroll
  for (int gi = 0; gi < 2; ++gi)
    #pragma unroll
    for (int nt = 0; nt < 4; ++nt)
      #pragma unroll
      for (int rq = 0; rq < 4; ++rq){
        const float4 bb = *reinterpret_cast<const float4*>(b1 + nt * 32 + rq * 8 + 4 * h);
        acc[gi][nt][rq*4+0] = fmaxf(acc[gi][nt][rq*4+0] + bb.x, 0.f);
        acc[gi][nt][rq*4+1] = fmaxf(acc[gi][nt][rq*4+1] + bb.y, 0.f);
        acc[gi][nt][rq*4+2] = fmaxf(acc[gi][nt][rq*4+2] + bb.z, 0.f);
        acc[gi][nt][rq*4+3] = fmaxf(acc[gi][nt][rq*4+3] + bb.w, 0.f);
      }

  // ---- in-register crossover (verified): D-layout -> B-frags for layer 2
  s16x8 b2fA[8], b2fB[8];
  #pragma unroll
  for (int gi = 0; gi < 2; ++gi){
    s16x8* b2f = gi ? b2fB : b2fA;
    #pragma unroll
    for (int nt = 0; nt < 4; ++nt)
      #pragma unroll
      for (int ks = 0; ks < 2; ++ks){
        const unsigned A0 = cvt_pk_bf16(acc[gi][nt][8*ks+0], acc[gi][nt][8*ks+1]);
        const unsigned A1 = cvt_pk_bf16(acc[gi][nt][8*ks+2], acc[gi][nt][8*ks+3]);
        const unsigned B0 = cvt_pk_bf16(acc[gi][nt][8*ks+4], acc[gi][nt][8*ks+5]);
        const unsigned B1 = cvt_pk_bf16(acc[gi][nt][8*ks+6], acc[gi][nt][8*ks+7]);
        const unsigned x0 = h ? A0 : B0;           // what the partner needs
        const unsigned x1 = h ? A1 : B1;
        const unsigned t0 = (unsigned)__shfl_xor((int)x0, 32);
        const unsigned t1 = (unsigned)__shfl_xor((int)x1, 32);
        u32x4 t;
        t[0] = h ? t0 : A0;
        t[1] = h ? t1 : A1;
        t[2] = h ? B0 : t0;
        t[3] = h ? B1 : t1;
        b2f[2*nt + ks] = __builtin_bit_cast(s16x8, t);
      }
  }

  // ---- layer 2: shared A-reads again
  #pragma unroll
  for (int gi = 0; gi < 2; ++gi)
    #pragma unroll
    for (int nt = 0; nt < 4; ++nt)
      #pragma unroll
      for (int r = 0; r < 16; ++r) acc[gi][nt][r] = 0.f;
  #pragma unroll
  for (int kf = 0; kf < 8; ++kf)
    #pragma unroll
    for (int nt = 0; nt < 4; ++nt){
      const s16x8 a = *reinterpret_cast<const s16x8*>(
          (const char*)wlds + 32768 + (kf * 4 + nt) * 1024 + lane * 16);
      acc[0][nt] = __builtin_amdgcn_mfma_f32_32x32x16_bf16(a, b2fA[kf], acc[0][nt], 0, 0, 0);
      acc[1][nt] = __builtin_amdgcn_mfma_f32_32x32x16_bf16(a, b2fB[kf], acc[1][nt], 0, 0, 0);
    }

  // ---- layer 3: bias+relu, dot W3, lane<->lane+32 reduce, sigmoid
  #pragma unroll
  for (int gi = 0; gi < 2; ++gi){
    float pv = 0.f;
    #pragma unroll
    for (int nt = 0; nt < 4; ++nt)
      #pragma unroll
      for (int rq = 0; rq < 4; ++rq){
        const int cb = nt * 32 + rq * 8 + 4 * h;
        const float4 bb = *reinterpret_cast<const float4*>(b2 + cb);
        const float4 ww = *reinterpret_cast<const float4*>(w3 + cb);
        pv += fmaxf(acc[gi][nt][rq*4+0] + bb.x, 0.f) * ww.x;
        pv += fmaxf(acc[gi][nt][rq*4+1] + bb.y, 0.f) * ww.y;
        pv += fmaxf(acc[gi][nt][rq*4+2] + bb.z, 0.f) * ww.z;
        pv += fmaxf(acc[gi][nt][rq*4+3] + bb.w, 0.f) * ww.w;
      }
    pv += __shfl_xor(pv, 32);
    const long g = gi ? g1 : g0;
    const bool v = gi ? v1 : v0;
    if (h == 0 && v){
      out[g * 32 + er] = 1.f / (1.f + expf(-(pv + bias3)));
    }
  }
}

// Fused 3-layer edge MLP.  Block = 4 waves x 2 passes x 2 groups (16 groups,
// 512 edges).  Pass 0's gathers issue BEFORE W-staging (latency hides under
// the 64KB stage); pass 1's gathers issue mid-pass-0 (intra-wave pipeline).
__global__ __launch_bounds__(256, 2) void mlp_main(
    const int* __restrict__ eidx,
    const unsigned char* __restrict__ nodef,   // [N][64] fp8 e4m3
    const unsigned short* __restrict__ wf,     // [2][32][512] bf16 frag-order
    const float* __restrict__ b1, const float* __restrict__ b2,
    const float* __restrict__ w3, const float* __restrict__ b3,
    float* __restrict__ out)
{
  __shared__ unsigned short wlds[32768];   // 64 KB: [layer][frag][lane*16B]

  const int tid  = threadIdx.x;
  const int wave = tid >> 6;
  const int lane = tid & 63;
  const int er   = lane & 31;   // edge-in-group / MFMA col
  const int h    = lane >> 5;   // k-half owner / feature half

  const long gb0 = (long)blockIdx.x * GPB + wave * 2;      // pass 0
  const long gb1 = gb0 + 8;                                // pass 1
  const bool p0v0 = (gb0     < NG), p0v1 = (gb0 + 1 < NG);
  const bool p1v0 = (gb1     < NG), p1v1 = (gb1 + 1 < NG);

  // ---- pass-0 idx + gathers FIRST (latency hides under W staging)
  u32x4 rA0[4], rB0[4], rA1[4], rB1[4];
  {
    const long ga = p0v0 ? gb0 : 0;
    const long gbq = p0v1 ? gb0 + 1 : 0;
    const int isA = eidx[ga * 32 + er];
    const int idA = eidx[N_EDGESC + ga * 32 + er];
    const int isB = eidx[gbq * 32 + er];
    const int idB = eidx[N_EDGESC + gbq * 32 + er];
    gather_fp8(nodef, isA, idA, h, rA0);
    gather_fp8(nodef, isB, idB, h, rB0);
  }

  // ---- stage BOTH W layers once (lane-linear, conflict-free)
  #pragma unroll
  for (int j = 0; j < 16; ++j){
    const int c = j * 256 + tid;
    reinterpret_cast<int4*>(wlds)[c] = reinterpret_cast<const int4*>(wf)[c];
  }
  __syncthreads();   // the only barrier

  const float bias3 = b3[0];

  do_pass<true >(wlds, lane, h, er, rA0, rB0, gb0, gb0 + 1, p0v0, p0v1,
                 nodef, eidx, gb1, gb1 + 1, rA1, rB1, b1, b2, w3, bias3, out);
  do_pass<false>(wlds, lane, h, er, rA1, rB1, gb1, gb1 + 1, p1v0, p1v1,
                 nodef, eidx, 0, 0, rA0, rB0, b1, b2, w3, bias3, out);
}

extern "C" void kernel_launch(void* const* d_in, const int* in_sizes, int n_in,
                              void* d_out, int out_size, void* d_ws, size_t ws_size,
                              hipStream_t stream){
  const float* node_rep = (const float*)d_in[0];
  const int*   eidx     = (const int*)d_in[1];
  const float* W1 = (const float*)d_in[2];
  const float* b1 = (const float*)d_in[3];
  const float* W2 = (const float*)d_in[4];
  const float* b2 = (const float*)d_in[5];
  const float* W3 = (const float*)d_in[6];
  const float* b3 = (const float*)d_in[7];
  float* out = (float*)d_out;

  unsigned* nodef = (unsigned*)d_ws;                                   // 6.4 MB fp8
  unsigned short* wf = (unsigned short*)((char*)d_ws + (size_t)N_NODES * NODE_DIM);

  prep_kernel<<<2048 + 128, 256, 0, stream>>>(node_rep, W1, W2, nodef, wf);

  const int nblocks = (NG + GPB - 1) / GPB;   // 1954
  mlp_main<<<nblocks, 256, 0, stream>>>(eidx, (const unsigned char*)nodef, wf,
                                        b1, b2, W3, b3, out);
}

// Round 9
// 188.836 us; speedup vs baseline: 2.7006x; 2.7006x over previous
//
#include <hip/hip_runtime.h>
#include <math.h>

typedef short s16x8 __attribute__((ext_vector_type(8)));
typedef float f32x16 __attribute__((ext_vector_type(16)));
typedef float f32x2 __attribute__((ext_vector_type(2)));
typedef unsigned u32x4 __attribute__((ext_vector_type(4)));
typedef unsigned u32x2 __attribute__((ext_vector_type(2)));

#define N_NODES 100000
#define N_EDGESC 1000000
#define NODE_DIM 64
#define NG 31250        // 1e6 / 32 edges per group (exact)
#define GPB 16          // groups per block (4 waves x 4 passes x 1 group)
#define NPASS 4
#define W1SCALE 32.0f   // power-of-2 scale keeps fp8(W1) out of subnormals
#define W1INV   0.03125f

// round-to-nearest-even f32 -> bf16 bits (prep only)
__device__ __forceinline__ unsigned short f2bf(float f){
  unsigned u = __float_as_uint(f);
  u += 0x7fffu + ((u >> 16) & 1u);
  return (unsigned short)(u >> 16);
}

// pack two f32 -> one u32 of 2x bf16 (RNE), single HW op
__device__ __forceinline__ unsigned cvt_pk_bf16(float lo, float hi){
  unsigned r;
  asm("v_cvt_pk_bf16_f32 %0, %1, %2" : "=v"(r) : "v"(lo), "v"(hi));
  return r;
}

// Prep: blocks [0,2048) cast node table f32 -> fp8 e4m3 (6.4 MB, 64B rows =
// one cache line).  Blocks [2048,2176):
//   i in [0,8192):      W1 -> fp8 frag-order, scaled x32.  Byte (f,l,j) holds
//                       fp8(32*W1[feat][n]), feat = (kf>>2)*64 + h*32 + (kf&3)*8 + j
//                       (k-rows permuted to match the contiguous fp8 feature gather)
//   i in [8192,24576):  W2 -> bf16 frag-order, plain k = kf*16 + h*8 + j
__global__ void prep_kernel(const float* __restrict__ node,
                            const float* __restrict__ w1,
                            const float* __restrict__ w2,
                            unsigned* __restrict__ nodef,        // fp8, 4 per u32
                            unsigned short* __restrict__ wf1,    // 8192 ushort = 16 KB fp8
                            unsigned short* __restrict__ wf2){   // 16384 ushort = 32 KB bf16
  const int b = blockIdx.x;
  if (b < 2048){
    int i = b * 256 + threadIdx.x;
    const int n4 = N_NODES * NODE_DIM / 4;
    const int stride = 2048 * 256;
    for (; i < n4; i += stride){
      const float4 v = reinterpret_cast<const float4*>(node)[i];
      unsigned lo = 0, hi = 0;
      asm("v_cvt_pk_fp8_f32 %0, %1, %2" : "+v"(lo) : "v"(v.x), "v"(v.y));
      asm("v_cvt_pk_fp8_f32 %0, %1, %2" : "+v"(hi) : "v"(v.z), "v"(v.w));
      nodef[i] = (lo & 0xffffu) | (hi << 16);
    }
  } else {
    const int i = (b - 2048) * 256 + threadIdx.x;
    if (i < 8192){
      // two consecutive fp8 bytes (j0, j0+1) of W1 fragment space
      const int bi = i * 2;
      const int f = bi >> 9, rem = bi & 511, l = rem >> 3, j0 = rem & 7;
      const int kf = f >> 2, nt = f & 3;
      const int h = l >> 5, n = nt * 32 + (l & 31);
      const int feat = (kf >> 2) * 64 + h * 32 + (kf & 3) * 8 + j0;
      const float v0 = W1SCALE * w1[feat * 128 + n];
      const float v1 = W1SCALE * w1[(feat + 1) * 128 + n];
      unsigned pk = 0;
      asm("v_cvt_pk_fp8_f32 %0, %1, %2" : "+v"(pk) : "v"(v0), "v"(v1));
      wf1[i] = (unsigned short)(pk & 0xffffu);
    } else if (i < 24576){
      const int i2 = i - 8192;
      const int f = i2 >> 9, rem = i2 & 511, l = rem >> 3, j = rem & 7;
      const int kf = f >> 2, nt = f & 3;
      const int h = l >> 5, n = nt * 32 + (l & 31);
      const int k = kf * 16 + h * 8 + j;
      wf2[i2] = f2bf(w2[k * 128 + n]);
    }
  }
}

__device__ __forceinline__ void gather_fp8(const unsigned char* __restrict__ nodef,
                                           int is, int id, int h, u32x4 (&r)[4]){
  const unsigned char* s = nodef + (size_t)is * 64 + h * 32;
  const unsigned char* d = nodef + (size_t)id * 64 + h * 32;
  r[0] = *reinterpret_cast<const u32x4*>(s);       // src feats h*32 .. +15
  r[1] = *reinterpret_cast<const u32x4*>(s + 16);  // src feats +16 .. +31
  r[2] = *reinterpret_cast<const u32x4*>(d);       // dst
  r[3] = *reinterpret_cast<const u32x4*>(d + 16);
}

// Fused 3-layer edge MLP.  Block = 4 waves x 4 passes x 1 group (16 groups,
// 512 edges).  48 KB LDS (W1 fp8 + W2 bf16) -> 3 blocks/CU = 12 waves/CU.
// Layer 1: mfma_f32_32x32x16_fp8_fp8, B-fragments taken DIRECTLY from the
// fp8 gather registers (no dequant).  acc scale 32 folded into the bias fma.
// Layer 2: verified bf16 path (in-register cvt_pk+shfl crossover).
// Pipelining with zero extra registers: next-pass idx loads at pass top,
// next-pass gather re-issued into the same r[] right after L1 consumes it.
__global__ __launch_bounds__(256, 3) void mlp_main(
    const int* __restrict__ eidx,
    const unsigned char* __restrict__ nodef,   // [N][64] fp8 e4m3
    const unsigned short* __restrict__ wf1,    // fp8 frag-order, 16 KB
    const unsigned short* __restrict__ wf2,    // bf16 frag-order, 32 KB
    const float* __restrict__ b1, const float* __restrict__ b2,
    const float* __restrict__ w3, const float* __restrict__ b3,
    float* __restrict__ out)
{
  __shared__ unsigned char  w1lds[16384];   // [32 frags][512 B]  fp8
  __shared__ unsigned short w2lds[16384];   // [32 frags][1024 B] bf16

  const int tid  = threadIdx.x;
  const int wave = tid >> 6;
  const int lane = tid & 63;
  const int er   = lane & 31;   // edge-in-group / MFMA col
  const int h    = lane >> 5;   // k-half owner / feature half

  // ---- pass-0 idx + gather FIRST (latency hides under W staging)
  u32x4 r[4];
  {
    const long g = (long)blockIdx.x * GPB + wave;
    const long gc = (g < NG) ? g : 0;
    const int is = eidx[gc * 32 + er];
    const int id = eidx[N_EDGESC + gc * 32 + er];
    gather_fp8(nodef, is, id, h, r);
  }

  // ---- stage W1 (16 KB) + W2 (32 KB), lane-linear, conflict-free
  #pragma unroll
  for (int j = 0; j < 4; ++j)
    reinterpret_cast<int4*>(w1lds)[j * 256 + tid] =
        reinterpret_cast<const int4*>(wf1)[j * 256 + tid];
  #pragma unroll
  for (int j = 0; j < 8; ++j)
    reinterpret_cast<int4*>(w2lds)[j * 256 + tid] =
        reinterpret_cast<const int4*>(wf2)[j * 256 + tid];
  __syncthreads();   // the only barrier

  const float bias3 = b3[0];

  #pragma unroll
  for (int p = 0; p < NPASS; ++p){
    const long g = (long)blockIdx.x * GPB + p * 4 + wave;
    const bool valid = (g < NG);

    // ---- next pass's indices (coalesced; latency hides under L1)
    int isn = 0, idn = 0;
    if (p + 1 < NPASS){
      const long gn = (long)blockIdx.x * GPB + (p + 1) * 4 + wave;
      const long gc = (gn < NG) ? gn : 0;
      isn = eidx[gc * 32 + er];
      idn = eidx[N_EDGESC + gc * 32 + er];
    }

    f32x16 acc[4];
    #pragma unroll
    for (int nt = 0; nt < 4; ++nt)
      #pragma unroll
      for (int q = 0; q < 16; ++q) acc[nt][q] = 0.f;

    // ---- layer 1 (fp8 x fp8): B straight from gather regs, A = ds_read_b64
    #pragma unroll
    for (int kf = 0; kf < 8; ++kf){
      const int dw = (kf >> 2) * 8 + (kf & 3) * 2;   // dword pair in r[]
      const unsigned blo = r[dw >> 2][dw & 3];
      const unsigned bhi = r[(dw + 1) >> 2][(dw + 1) & 3];
      const long bfr = (long)(((unsigned long long)bhi << 32) | blo);
      #pragma unroll
      for (int nt = 0; nt < 4; ++nt){
        const u32x2 av = *reinterpret_cast<const u32x2*>(
            w1lds + (kf * 4 + nt) * 512 + lane * 8);
        const long a = (long)(((unsigned long long)av[1] << 32) | av[0]);
        acc[nt] = __builtin_amdgcn_mfma_f32_32x32x16_fp8_fp8(a, bfr, acc[nt], 0, 0, 0);
      }
    }

    // ---- r dead: re-issue gather for next pass into the SAME buffer
    if (p + 1 < NPASS) gather_fp8(nodef, isn, idn, h, r);

    // ---- bias (scale 1/32 folded) + relu in place
    #pragma unroll
    for (int nt = 0; nt < 4; ++nt)
      #pragma unroll
      for (int rq = 0; rq < 4; ++rq){
        const float4 bb = *reinterpret_cast<const float4*>(b1 + nt * 32 + rq * 8 + 4 * h);
        acc[nt][rq*4+0] = fmaxf(fmaf(acc[nt][rq*4+0], W1INV, bb.x), 0.f);
        acc[nt][rq*4+1] = fmaxf(fmaf(acc[nt][rq*4+1], W1INV, bb.y), 0.f);
        acc[nt][rq*4+2] = fmaxf(fmaf(acc[nt][rq*4+2], W1INV, bb.z), 0.f);
        acc[nt][rq*4+3] = fmaxf(fmaf(acc[nt][rq*4+3], W1INV, bb.w), 0.f);
      }

    // ---- in-register crossover (verified): D-layout -> bf16 B-frags
    s16x8 b2f[8];
    #pragma unroll
    for (int nt = 0; nt < 4; ++nt)
      #pragma unroll
      for (int ks = 0; ks < 2; ++ks){
        const unsigned A0 = cvt_pk_bf16(acc[nt][8*ks+0], acc[nt][8*ks+1]);
        const unsigned A1 = cvt_pk_bf16(acc[nt][8*ks+2], acc[nt][8*ks+3]);
        const unsigned B0 = cvt_pk_bf16(acc[nt][8*ks+4], acc[nt][8*ks+5]);
        const unsigned B1 = cvt_pk_bf16(acc[nt][8*ks+6], acc[nt][8*ks+7]);
        const unsigned x0 = h ? A0 : B0;           // what the partner needs
        const unsigned x1 = h ? A1 : B1;
        const unsigned t0 = (unsigned)__shfl_xor((int)x0, 32);
        const unsigned t1 = (unsigned)__shfl_xor((int)x1, 32);
        u32x4 t;
        t[0] = h ? t0 : A0;
        t[1] = h ? t1 : A1;
        t[2] = h ? B0 : t0;
        t[3] = h ? B1 : t1;
        b2f[2*nt + ks] = __builtin_bit_cast(s16x8, t);
      }

    // ---- layer 2 (bf16, verified)
    #pragma unroll
    for (int nt = 0; nt < 4; ++nt)
      #pragma unroll
      for (int q = 0; q < 16; ++q) acc[nt][q] = 0.f;
    #pragma unroll
    for (int kf = 0; kf < 8; ++kf)
      #pragma unroll
      for (int nt = 0; nt < 4; ++nt){
        const s16x8 a = *reinterpret_cast<const s16x8*>(
            (const char*)w2lds + (kf * 4 + nt) * 1024 + lane * 16);
        acc[nt] = __builtin_amdgcn_mfma_f32_32x32x16_bf16(a, b2f[kf], acc[nt], 0, 0, 0);
      }

    // ---- layer 3: bias+relu, dot W3, lane<->lane+32 reduce, sigmoid
    float pv = 0.f;
    #pragma unroll
    for (int nt = 0; nt < 4; ++nt)
      #pragma unroll
      for (int rq = 0; rq < 4; ++rq){
        const int cb = nt * 32 + rq * 8 + 4 * h;
        const float4 bb = *reinterpret_cast<const float4*>(b2 + cb);
        const float4 ww = *reinterpret_cast<const float4*>(w3 + cb);
        pv += fmaxf(acc[nt][rq*4+0] + bb.x, 0.f) * ww.x;
        pv += fmaxf(acc[nt][rq*4+1] + bb.y, 0.f) * ww.y;
        pv += fmaxf(acc[nt][rq*4+2] + bb.z, 0.f) * ww.z;
        pv += fmaxf(acc[nt][rq*4+3] + bb.w, 0.f) * ww.w;
      }
    pv += __shfl_xor(pv, 32);
    if (h == 0 && valid){
      out[g * 32 + er] = 1.f / (1.f + expf(-(pv + bias3)));
    }
  }
}

extern "C" void kernel_launch(void* const* d_in, const int* in_sizes, int n_in,
                              void* d_out, int out_size, void* d_ws, size_t ws_size,
                              hipStream_t stream){
  const float* node_rep = (const float*)d_in[0];
  const int*   eidx     = (const int*)d_in[1];
  const float* W1 = (const float*)d_in[2];
  const float* b1 = (const float*)d_in[3];
  const float* W2 = (const float*)d_in[4];
  const float* b2 = (const float*)d_in[5];
  const float* W3 = (const float*)d_in[6];
  const float* b3 = (const float*)d_in[7];
  float* out = (float*)d_out;

  unsigned* nodef = (unsigned*)d_ws;                                    // 6.4 MB fp8
  unsigned short* wf1 = (unsigned short*)((char*)d_ws + (size_t)N_NODES * NODE_DIM);
  unsigned short* wf2 = wf1 + 8192;

  prep_kernel<<<2048 + 128, 256, 0, stream>>>(node_rep, W1, W2, nodef, wf1, wf2);

  const int nblocks = (NG + GPB - 1) / GPB;   // 1954
  mlp_main<<<nblocks, 256, 0, stream>>>(eidx, (const unsigned char*)nodef,
                                        wf1, wf2, b1, b2, W3, b3, out);
}

// Round 10
// 158.873 us; speedup vs baseline: 3.2099x; 1.1886x over previous
//
#include <hip/hip_runtime.h>
#include <math.h>

typedef float f32x16 __attribute__((ext_vector_type(16)));
typedef unsigned u32x4 __attribute__((ext_vector_type(4)));
typedef unsigned u32x2 __attribute__((ext_vector_type(2)));

#define N_NODES 100000
#define N_EDGESC 1000000
#define NODE_DIM 64
#define NG 31250            // 1e6 / 32 edges per group
#define GPB 16              // 4 waves x 2 groups x 2 passes
#define L1FOLD 0.5f         // acc1*(16/32): h1s = relu(acc1*0.5 + 16*b1)
#define L2FOLD 0.001953125f // 1/512 = 1/(16*32)

// round-to-nearest-even f32 -> bf16 bits (unused in main path, kept for prep clarity)
__device__ __forceinline__ unsigned short f2bf(float f){
  unsigned u = __float_as_uint(f);
  u += 0x7fffu + ((u >> 16) & 1u);
  return (unsigned short)(u >> 16);
}

// pack 4 f32 -> 4 fp8 e4m3 bytes in one u32 (two HW cvt_pk ops)
__device__ __forceinline__ unsigned pk4_fp8(float a, float b, float c, float d){
  unsigned lo = 0, hi = 0;
  asm("v_cvt_pk_fp8_f32 %0, %1, %2" : "+v"(lo) : "v"(a), "v"(b));
  asm("v_cvt_pk_fp8_f32 %0, %1, %2" : "+v"(hi) : "v"(c), "v"(d));
  return (lo & 0xffffu) | (hi << 16);
}

__device__ __forceinline__ long pack64(unsigned lo, unsigned hi){
  return (long)(((unsigned long long)hi << 32) | lo);
}

// Prep: blocks [0,2048) cast node table f32 -> fp8 e4m3 (6.4 MB, 64B rows).
// Blocks [2048,2176):
//   i in [0,8192):     W1 fp8 frag-order (x32), k-rows permuted for the
//                      contiguous feature gather: feat = (kf>>2)*64 + h*32 + (kf&3)*8 + j
//   i in [8192,16384): W2 fp8 frag-order (x32), plain k = kf*16 + h*8 + j
//   i in [16384,16512): b1s = 16*b1
__global__ void prep_kernel(const float* __restrict__ node,
                            const float* __restrict__ w1,
                            const float* __restrict__ w2,
                            const float* __restrict__ b1,
                            unsigned* __restrict__ nodef,
                            unsigned short* __restrict__ wf,   // 16384 ushort = 32 KB
                            float* __restrict__ b1s){
  const int b = blockIdx.x;
  if (b < 2048){
    int i = b * 256 + threadIdx.x;
    const int n4 = N_NODES * NODE_DIM / 4;
    const int stride = 2048 * 256;
    for (; i < n4; i += stride){
      const float4 v = reinterpret_cast<const float4*>(node)[i];
      unsigned lo = 0, hi = 0;
      asm("v_cvt_pk_fp8_f32 %0, %1, %2" : "+v"(lo) : "v"(v.x), "v"(v.y));
      asm("v_cvt_pk_fp8_f32 %0, %1, %2" : "+v"(hi) : "v"(v.z), "v"(v.w));
      nodef[i] = (lo & 0xffffu) | (hi << 16);
    }
  } else {
    const int i = (b - 2048) * 256 + threadIdx.x;
    if (i < 16384){
      const int isW2 = (i >> 13) & 1;          // 0: W1, 1: W2
      const int bi = (i & 8191) * 2;           // byte index in frag space
      const int f = bi >> 9, rem = bi & 511, l = rem >> 3, j0 = rem & 7;
      const int kf = f >> 2, nt = f & 3;
      const int h = l >> 5, n = nt * 32 + (l & 31);
      float v0, v1;
      if (!isW2){
        const int feat = (kf >> 2) * 64 + h * 32 + (kf & 3) * 8 + j0;
        v0 = 32.0f * w1[feat * 128 + n];
        v1 = 32.0f * w1[(feat + 1) * 128 + n];
      } else {
        const int k = kf * 16 + h * 8 + j0;
        v0 = 32.0f * w2[k * 128 + n];
        v1 = 32.0f * w2[(k + 1) * 128 + n];
      }
      unsigned pk = 0;
      asm("v_cvt_pk_fp8_f32 %0, %1, %2" : "+v"(pk) : "v"(v0), "v"(v1));
      wf[i] = (unsigned short)(pk & 0xffffu);
    } else if (i < 16512){
      b1s[i - 16384] = 16.0f * b1[i - 16384];
    }
  }
}

__device__ __forceinline__ void gather_fp8(const unsigned char* __restrict__ nodef,
                                           int is, int id, int h, u32x4 (&r)[4]){
  const unsigned char* s = nodef + (size_t)is * 64 + h * 32;
  const unsigned char* d = nodef + (size_t)id * 64 + h * 32;
  r[0] = *reinterpret_cast<const u32x4*>(s);
  r[1] = *reinterpret_cast<const u32x4*>(s + 16);
  r[2] = *reinterpret_cast<const u32x4*>(d);
  r[3] = *reinterpret_cast<const u32x4*>(d + 16);
}

// One pass over 2 groups (64 edges).  L1: fp8xfp8 MFMA, B straight from the
// gather regs (HW-verified R9).  Crossover: h1 -> fp8 (x16) fully in-register:
// channel c5 = (q&3) + 4*hh + 8*(q>>2)  =>  for L2 frag kf, lane (er,h) needs
// q = (j&3) + 8*(kf&1) + 4h, dword0 from hh=0 lane, dword1 from hh=1 lane.
// One shfl_xor(.,32) per 2 frags.  L2: fp8xfp8 MFMA.  Scales fold into biases.
// If PF: next pass's idx loads at top, gathers re-issued into the SAME gA/gB
// right after L1 consumes them (zero extra registers).
template<bool PF>
__device__ __forceinline__ void do_pass(
    const unsigned char* wlds, int lane, int h, int er,
    u32x4 (&gA)[4], u32x4 (&gB)[4], long g0, bool v0, bool v1,
    const unsigned char* __restrict__ nodef, const int* __restrict__ eidx,
    long gn0,
    const float* __restrict__ b1s, const float* __restrict__ b2,
    const float* __restrict__ w3, float bias3, float* __restrict__ out)
{
  int isAn = 0, idAn = 0, isBn = 0, idBn = 0;
  if (PF){
    const long ga = (gn0 < NG) ? gn0 : 0;
    const long gb = (gn0 + 1 < NG) ? gn0 + 1 : 0;
    isAn = eidx[ga * 32 + er];
    idAn = eidx[N_EDGESC + ga * 32 + er];
    isBn = eidx[gb * 32 + er];
    idBn = eidx[N_EDGESC + gb * 32 + er];
  }

  f32x16 acc[2][4];
  #pragma unroll
  for (int gi = 0; gi < 2; ++gi)
    #pragma unroll
    for (int nt = 0; nt < 4; ++nt)
      #pragma unroll
      for (int q = 0; q < 16; ++q) acc[gi][nt][q] = 0.f;

  // ---- layer 1 (fp8 x fp8): A = ds_read_b64, B from gather regs
  __builtin_amdgcn_s_setprio(1);
  #pragma unroll
  for (int kf = 0; kf < 8; ++kf){
    const int dw = (kf >> 2) * 8 + (kf & 3) * 2;
    const long bA = pack64(gA[dw >> 2][dw & 3], gA[(dw + 1) >> 2][(dw + 1) & 3]);
    const long bB = pack64(gB[dw >> 2][dw & 3], gB[(dw + 1) >> 2][(dw + 1) & 3]);
    #pragma unroll
    for (int nt = 0; nt < 4; ++nt){
      const u32x2 av = *reinterpret_cast<const u32x2*>(wlds + (kf * 4 + nt) * 512 + lane * 8);
      const long a = pack64(av[0], av[1]);
      acc[0][nt] = __builtin_amdgcn_mfma_f32_32x32x16_fp8_fp8(a, bA, acc[0][nt], 0, 0, 0);
      acc[1][nt] = __builtin_amdgcn_mfma_f32_32x32x16_fp8_fp8(a, bB, acc[1][nt], 0, 0, 0);
    }
  }
  __builtin_amdgcn_s_setprio(0);

  // ---- gA/gB dead: re-issue next pass's gathers into the SAME buffers
  if (PF){
    gather_fp8(nodef, isAn, idAn, h, gA);
    gather_fp8(nodef, isBn, idBn, h, gB);
  }

  // ---- scaled bias + relu:  h1s = relu(acc*0.5 + 16*b1)
  #pragma unroll
  for (int gi = 0; gi < 2; ++gi)
    #pragma unroll
    for (int nt = 0; nt < 4; ++nt)
      #pragma unroll
      for (int rq = 0; rq < 4; ++rq){
        const float4 bb = *reinterpret_cast<const float4*>(b1s + nt * 32 + rq * 8 + 4 * h);
        acc[gi][nt][rq*4+0] = fmaxf(fmaf(acc[gi][nt][rq*4+0], L1FOLD, bb.x), 0.f);
        acc[gi][nt][rq*4+1] = fmaxf(fmaf(acc[gi][nt][rq*4+1], L1FOLD, bb.y), 0.f);
        acc[gi][nt][rq*4+2] = fmaxf(fmaf(acc[gi][nt][rq*4+2], L1FOLD, bb.z), 0.f);
        acc[gi][nt][rq*4+3] = fmaxf(fmaf(acc[gi][nt][rq*4+3], L1FOLD, bb.w), 0.f);
      }

  // ---- in-register crossover to fp8 B-frags (u32x2 per frag)
  u32x2 b2fA[8], b2fB[8];
  #pragma unroll
  for (int gi = 0; gi < 2; ++gi){
    u32x2* b2f = gi ? b2fB : b2fA;
    #pragma unroll
    for (int nt = 0; nt < 4; ++nt){
      const unsigned u0 = pk4_fp8(acc[gi][nt][0],  acc[gi][nt][1],  acc[gi][nt][2],  acc[gi][nt][3]);
      const unsigned u1 = pk4_fp8(acc[gi][nt][4],  acc[gi][nt][5],  acc[gi][nt][6],  acc[gi][nt][7]);
      const unsigned u2 = pk4_fp8(acc[gi][nt][8],  acc[gi][nt][9],  acc[gi][nt][10], acc[gi][nt][11]);
      const unsigned u3 = pk4_fp8(acc[gi][nt][12], acc[gi][nt][13], acc[gi][nt][14], acc[gi][nt][15]);
      const unsigned s0 = h ? u0 : u1;                 // partner's need, s=0
      const unsigned s1 = h ? u2 : u3;                 // partner's need, s=1
      const unsigned t0 = (unsigned)__shfl_xor((int)s0, 32);
      const unsigned t1 = (unsigned)__shfl_xor((int)s1, 32);
      u32x2 f0, f1;
      f0[0] = h ? t0 : u0;  f0[1] = h ? u1 : t0;       // frag 2nt
      f1[0] = h ? t1 : u2;  f1[1] = h ? u3 : t1;       // frag 2nt+1
      b2f[2*nt]     = f0;
      b2f[2*nt + 1] = f1;
    }
  }

  // ---- layer 2 (fp8 x fp8)
  #pragma unroll
  for (int gi = 0; gi < 2; ++gi)
    #pragma unroll
    for (int nt = 0; nt < 4; ++nt)
      #pragma unroll
      for (int q = 0; q < 16; ++q) acc[gi][nt][q] = 0.f;
  __builtin_amdgcn_s_setprio(1);
  #pragma unroll
  for (int kf = 0; kf < 8; ++kf){
    const long bA = pack64(b2fA[kf][0], b2fA[kf][1]);
    const long bB = pack64(b2fB[kf][0], b2fB[kf][1]);
    #pragma unroll
    for (int nt = 0; nt < 4; ++nt){
      const u32x2 av = *reinterpret_cast<const u32x2*>(wlds + 16384 + (kf * 4 + nt) * 512 + lane * 8);
      const long a = pack64(av[0], av[1]);
      acc[0][nt] = __builtin_amdgcn_mfma_f32_32x32x16_fp8_fp8(a, bA, acc[0][nt], 0, 0, 0);
      acc[1][nt] = __builtin_amdgcn_mfma_f32_32x32x16_fp8_fp8(a, bB, acc[1][nt], 0, 0, 0);
    }
  }
  __builtin_amdgcn_s_setprio(0);

  // ---- layer 3: fold 1/512, bias+relu, dot W3, lane<->lane+32 reduce, sigmoid
  #pragma unroll
  for (int gi = 0; gi < 2; ++gi){
    float pv = 0.f;
    #pragma unroll
    for (int nt = 0; nt < 4; ++nt)
      #pragma unroll
      for (int rq = 0; rq < 4; ++rq){
        const int cb = nt * 32 + rq * 8 + 4 * h;
        const float4 bb = *reinterpret_cast<const float4*>(b2 + cb);
        const float4 ww = *reinterpret_cast<const float4*>(w3 + cb);
        pv += fmaxf(fmaf(acc[gi][nt][rq*4+0], L2FOLD, bb.x), 0.f) * ww.x;
        pv += fmaxf(fmaf(acc[gi][nt][rq*4+1], L2FOLD, bb.y), 0.f) * ww.y;
        pv += fmaxf(fmaf(acc[gi][nt][rq*4+2], L2FOLD, bb.z), 0.f) * ww.z;
        pv += fmaxf(fmaf(acc[gi][nt][rq*4+3], L2FOLD, bb.w), 0.f) * ww.w;
      }
    pv += __shfl_xor(pv, 32);
    const long g = g0 + gi;
    const bool v = gi ? v1 : v0;
    if (h == 0 && v){
      out[g * 32 + er] = 1.f / (1.f + expf(-(pv + bias3)));
    }
  }
}

// Block = 4 waves x 2 passes x 2 groups (16 groups, 512 edges).  32 KB LDS
// (W1+W2 fp8 frag-order), zero barriers after staging, 2 blocks/CU.
__global__ __launch_bounds__(256, 2) void mlp_main(
    const int* __restrict__ eidx,
    const unsigned char* __restrict__ nodef,
    const unsigned short* __restrict__ wf,
    const float* __restrict__ b1s, const float* __restrict__ b2,
    const float* __restrict__ w3, const float* __restrict__ b3,
    float* __restrict__ out)
{
  __shared__ unsigned char wlds[32768];   // [W1 16KB][W2 16KB] fp8 frag-order

  const int tid  = threadIdx.x;
  const int wave = tid >> 6;
  const int lane = tid & 63;
  const int er   = lane & 31;
  const int h    = lane >> 5;

  const long g0 = (long)blockIdx.x * GPB + wave * 2;       // pass 0 pair
  const long g1 = g0 + 8;                                  // pass 1 pair
  const bool p0v0 = (g0 < NG),     p0v1 = (g0 + 1 < NG);
  const bool p1v0 = (g1 < NG),     p1v1 = (g1 + 1 < NG);

  // ---- pass-0 idx + gathers FIRST (latency hides under W staging)
  u32x4 gA[4], gB[4];
  {
    const long ga = p0v0 ? g0 : 0;
    const long gb = p0v1 ? g0 + 1 : 0;
    const int isA = eidx[ga * 32 + er];
    const int idA = eidx[N_EDGESC + ga * 32 + er];
    const int isB = eidx[gb * 32 + er];
    const int idB = eidx[N_EDGESC + gb * 32 + er];
    gather_fp8(nodef, isA, idA, h, gA);
    gather_fp8(nodef, isB, idB, h, gB);
  }

  // ---- stage W1+W2 (32 KB, lane-linear, conflict-free)
  #pragma unroll
  for (int j = 0; j < 8; ++j)
    reinterpret_cast<int4*>(wlds)[j * 256 + tid] =
        reinterpret_cast<const int4*>(wf)[j * 256 + tid];
  __syncthreads();   // the only barrier

  const float bias3 = b3[0];

  do_pass<true >(wlds, lane, h, er, gA, gB, g0, p0v0, p0v1,
                 nodef, eidx, g1, b1s, b2, w3, bias3, out);
  do_pass<false>(wlds, lane, h, er, gA, gB, g1, p1v0, p1v1,
                 nodef, eidx, 0, b1s, b2, w3, bias3, out);
}

extern "C" void kernel_launch(void* const* d_in, const int* in_sizes, int n_in,
                              void* d_out, int out_size, void* d_ws, size_t ws_size,
                              hipStream_t stream){
  const float* node_rep = (const float*)d_in[0];
  const int*   eidx     = (const int*)d_in[1];
  const float* W1 = (const float*)d_in[2];
  const float* b1 = (const float*)d_in[3];
  const float* W2 = (const float*)d_in[4];
  const float* b2 = (const float*)d_in[5];
  const float* W3 = (const float*)d_in[6];
  const float* b3 = (const float*)d_in[7];
  float* out = (float*)d_out;

  unsigned* nodef = (unsigned*)d_ws;                                        // 6.4 MB fp8
  unsigned short* wf = (unsigned short*)((char*)d_ws + (size_t)N_NODES * NODE_DIM);
  float* b1s = (float*)((char*)d_ws + (size_t)N_NODES * NODE_DIM + 32768);

  prep_kernel<<<2048 + 128, 256, 0, stream>>>(node_rep, W1, W2, b1, nodef, wf, b1s);

  const int nblocks = (NG + GPB - 1) / GPB;   // 1954
  mlp_main<<<nblocks, 256, 0, stream>>>(eidx, (const unsigned char*)nodef, wf,
                                        b1s, b2, W3, b3, out);
}

// Round 11
// 146.915 us; speedup vs baseline: 3.4711x; 1.0814x over previous
//
#include <hip/hip_runtime.h>
#include <math.h>

typedef float f32x16 __attribute__((ext_vector_type(16)));
typedef unsigned u32x4 __attribute__((ext_vector_type(4)));
typedef unsigned u32x2 __attribute__((ext_vector_type(2)));

#define N_NODES 100000
#define N_EDGESC 1000000
#define NODE_DIM 64
#define NG 31250            // 1e6 / 32 edges per group
#define GPB 16              // 4 waves x 2 groups x 2 passes
#define WBYTES 36864        // 2 layers x 36 frags x 512 B
#define BLOB (WBYTES + 512) // + w3s (128 f32)

// pack 2 f32 -> fp8 e4m3 pair into lo or hi word of r
__device__ __forceinline__ unsigned pk2_lo(float a, float b){
#if __has_builtin(__builtin_amdgcn_cvt_pk_fp8_f32)
  return (unsigned)__builtin_amdgcn_cvt_pk_fp8_f32(a, b, 0, false);
#else
  unsigned r = 0;
  asm("v_cvt_pk_fp8_f32 %0, %1, %2" : "+v"(r) : "v"(a), "v"(b));
  return r;
#endif
}
__device__ __forceinline__ unsigned pk2_hi(float a, float b, unsigned old){
#if __has_builtin(__builtin_amdgcn_cvt_pk_fp8_f32)
  return (unsigned)__builtin_amdgcn_cvt_pk_fp8_f32(a, b, (int)old, true);
#else
  asm("v_cvt_pk_fp8_f32 %0, %1, %2 op_sel:[0,0,1]" : "+v"(old) : "v"(a), "v"(b));
  return old;
#endif
}
__device__ __forceinline__ unsigned pk4_fp8(float a, float b, float c, float d){
  return pk2_hi(c, d, pk2_lo(a, b));
}

__device__ __forceinline__ long pack64(unsigned lo, unsigned hi){
  return (long)(((unsigned long long)hi << 32) | lo);
}

// Prep: blocks [0,2048) cast node table f32 -> fp8 e4m3 (6.4 MB, 64B rows).
// Blocks [2048,...): build the 37376-B weight blob:
//   bytes [0,18432):      W1 fp8 frag-order (x32), 9 kf-blocks (K=144).
//     kf<8: k-rows permuted for the contiguous gather:
//           feat = (kf>>2)*64 + h*32 + (kf&3)*8 + j
//     kf=8: bias block  A = (h==0 && j==0) ? 2*b1[n] : 0
//   bytes [18432,36864):  W2 fp8 frag-order (x32), plain k = kf*16+h*8+j,
//     kf=8: bias block  A = (h==0 && j==0) ? 64*b2[n] : 0
//   bytes [36864,37376):  w3s = w3 / 1024  (f32)
__global__ void prep_kernel(const float* __restrict__ node,
                            const float* __restrict__ w1,
                            const float* __restrict__ w2,
                            const float* __restrict__ b1,
                            const float* __restrict__ b2,
                            const float* __restrict__ w3,
                            unsigned* __restrict__ nodef,
                            unsigned short* __restrict__ wfp,   // byte pairs
                            float* __restrict__ w3s){
  const int b = blockIdx.x;
  if (b < 2048){
    int i = b * 256 + threadIdx.x;
    const int n4 = N_NODES * NODE_DIM / 4;
    const int stride = 2048 * 256;
    for (; i < n4; i += stride){
      const float4 v = reinterpret_cast<const float4*>(node)[i];
      nodef[i] = pk4_fp8(v.x, v.y, v.z, v.w);
    }
  } else {
    const int i = (b - 2048) * 256 + threadIdx.x;
    if (i < 18432){
      const int bi = i * 2;                      // byte index in W space
      const int layer = (bi >= 18432);
      const int off = bi - (layer ? 18432 : 0);
      const int f = off >> 9, rem = off & 511, l = rem >> 3, j0 = rem & 7;
      const int kf = f >> 2, nt = f & 3;
      const int h = l >> 5, n = nt * 32 + (l & 31);
      float v0, v1;
      if (kf < 8){
        if (!layer){
          const int feat = (kf >> 2) * 64 + h * 32 + (kf & 3) * 8 + j0;
          v0 = 32.0f * w1[feat * 128 + n];
          v1 = 32.0f * w1[(feat + 1) * 128 + n];
        } else {
          const int k = kf * 16 + h * 8 + j0;
          v0 = 32.0f * w2[k * 128 + n];
          v1 = 32.0f * w2[(k + 1) * 128 + n];
        }
      } else {
        v0 = (h == 0 && j0 == 0) ? (layer ? 64.0f * b2[n] : 2.0f * b1[n]) : 0.0f;
        v1 = 0.0f;
      }
      wfp[i] = (unsigned short)(pk2_lo(v0, v1) & 0xffffu);
    } else if (i < 18432 + 128){
      const int c = i - 18432;
      w3s[c] = w3[c] * 0.0009765625f;   // 1/1024
    }
  }
}

__device__ __forceinline__ void gather_fp8(const unsigned char* __restrict__ nodef,
                                           int is, int id, int h, u32x4 (&r)[4]){
  const unsigned char* s = nodef + (size_t)is * 64 + h * 32;
  const unsigned char* d = nodef + (size_t)id * 64 + h * 32;
  r[0] = *reinterpret_cast<const u32x4*>(s);
  r[1] = *reinterpret_cast<const u32x4*>(s + 16);
  r[2] = *reinterpret_cast<const u32x4*>(d);
  r[3] = *reinterpret_cast<const u32x4*>(d + 16);
}

// One pass over 2 groups (64 edges).  All scales/biases live in the MFMA:
//   acc1 = 32*(feat.w1 + b1)   (K=144: bias block, B = const fp8(16) at k=128)
//   h1s  = fp8(relu(acc1))                       [scale 32, exact since relu(s x)=s relu(x)]
//   acc2 = 1024*(h1.w2 + b2)   (K=144, same constant B bias block)
//   pv   = sum fmax(acc2,0)*w3s                  [w3s = w3/1024 from LDS]
// If PF: next pass's idx at top, gathers re-issued into the SAME gA/gB after L1.
template<bool PF>
__device__ __forceinline__ void do_pass(
    const unsigned char* wlds, int lane, int h, int er,
    u32x4 (&gA)[4], u32x4 (&gB)[4], long g0, bool v0, bool v1,
    const unsigned char* __restrict__ nodef, const int* __restrict__ eidx,
    long gn0, float bias3, float* __restrict__ out)
{
  int isAn = 0, idAn = 0, isBn = 0, idBn = 0;
  if (PF){
    const long ga = (gn0 < NG) ? gn0 : 0;
    const long gb = (gn0 + 1 < NG) ? gn0 + 1 : 0;
    isAn = eidx[ga * 32 + er];
    idAn = eidx[N_EDGESC + ga * 32 + er];
    isBn = eidx[gb * 32 + er];
    idBn = eidx[N_EDGESC + gb * 32 + er];
  }

  const long bbias = (h == 0) ? 0x58L : 0L;   // fp8 e4m3(16.0) in byte0, h=0 lanes

  f32x16 acc[2][4];
  #pragma unroll
  for (int gi = 0; gi < 2; ++gi)
    #pragma unroll
    for (int nt = 0; nt < 4; ++nt)
      #pragma unroll
      for (int q = 0; q < 16; ++q) acc[gi][nt][q] = 0.f;

  // ---- layer 1 (fp8 x fp8): A = ds_read_b64, B from gather regs + bias block
  __builtin_amdgcn_s_setprio(1);
  #pragma unroll
  for (int kf = 0; kf < 8; ++kf){
    const int dw = (kf >> 2) * 8 + (kf & 3) * 2;
    const long bA = pack64(gA[dw >> 2][dw & 3], gA[(dw + 1) >> 2][(dw + 1) & 3]);
    const long bB = pack64(gB[dw >> 2][dw & 3], gB[(dw + 1) >> 2][(dw + 1) & 3]);
    #pragma unroll
    for (int nt = 0; nt < 4; ++nt){
      const u32x2 av = *reinterpret_cast<const u32x2*>(wlds + (kf * 4 + nt) * 512 + lane * 8);
      const long a = pack64(av[0], av[1]);
      acc[0][nt] = __builtin_amdgcn_mfma_f32_32x32x16_fp8_fp8(a, bA, acc[0][nt], 0, 0, 0);
      acc[1][nt] = __builtin_amdgcn_mfma_f32_32x32x16_fp8_fp8(a, bB, acc[1][nt], 0, 0, 0);
    }
  }
  #pragma unroll
  for (int nt = 0; nt < 4; ++nt){   // bias block kf=8
    const u32x2 av = *reinterpret_cast<const u32x2*>(wlds + (32 + nt) * 512 + lane * 8);
    const long a = pack64(av[0], av[1]);
    acc[0][nt] = __builtin_amdgcn_mfma_f32_32x32x16_fp8_fp8(a, bbias, acc[0][nt], 0, 0, 0);
    acc[1][nt] = __builtin_amdgcn_mfma_f32_32x32x16_fp8_fp8(a, bbias, acc[1][nt], 0, 0, 0);
  }
  __builtin_amdgcn_s_setprio(0);

  // ---- gA/gB dead: re-issue next pass's gathers into the SAME buffers
  if (PF){
    gather_fp8(nodef, isAn, idAn, h, gA);
    gather_fp8(nodef, isBn, idBn, h, gB);
  }

  // ---- relu in place (no scale/bias VALU left)
  #pragma unroll
  for (int gi = 0; gi < 2; ++gi)
    #pragma unroll
    for (int nt = 0; nt < 4; ++nt)
      #pragma unroll
      for (int q = 0; q < 16; ++q)
        acc[gi][nt][q] = fmaxf(acc[gi][nt][q], 0.f);

  // ---- in-register crossover to fp8 B-frags (verified R10 mapping)
  u32x2 b2fA[8], b2fB[8];
  #pragma unroll
  for (int gi = 0; gi < 2; ++gi){
    u32x2* b2f = gi ? b2fB : b2fA;
    #pragma unroll
    for (int nt = 0; nt < 4; ++nt){
      const unsigned u0 = pk4_fp8(acc[gi][nt][0],  acc[gi][nt][1],  acc[gi][nt][2],  acc[gi][nt][3]);
      const unsigned u1 = pk4_fp8(acc[gi][nt][4],  acc[gi][nt][5],  acc[gi][nt][6],  acc[gi][nt][7]);
      const unsigned u2 = pk4_fp8(acc[gi][nt][8],  acc[gi][nt][9],  acc[gi][nt][10], acc[gi][nt][11]);
      const unsigned u3 = pk4_fp8(acc[gi][nt][12], acc[gi][nt][13], acc[gi][nt][14], acc[gi][nt][15]);
      const unsigned s0 = h ? u0 : u1;
      const unsigned s1 = h ? u2 : u3;
      const unsigned t0 = (unsigned)__shfl_xor((int)s0, 32);
      const unsigned t1 = (unsigned)__shfl_xor((int)s1, 32);
      u32x2 f0, f1;
      f0[0] = h ? t0 : u0;  f0[1] = h ? u1 : t0;
      f1[0] = h ? t1 : u2;  f1[1] = h ? u3 : t1;
      b2f[2*nt]     = f0;
      b2f[2*nt + 1] = f1;
    }
  }

  // ---- layer 2 (fp8 x fp8) + bias block
  #pragma unroll
  for (int gi = 0; gi < 2; ++gi)
    #pragma unroll
    for (int nt = 0; nt < 4; ++nt)
      #pragma unroll
      for (int q = 0; q < 16; ++q) acc[gi][nt][q] = 0.f;
  __builtin_amdgcn_s_setprio(1);
  #pragma unroll
  for (int kf = 0; kf < 8; ++kf){
    const long bA = pack64(b2fA[kf][0], b2fA[kf][1]);
    const long bB = pack64(b2fB[kf][0], b2fB[kf][1]);
    #pragma unroll
    for (int nt = 0; nt < 4; ++nt){
      const u32x2 av = *reinterpret_cast<const u32x2*>(wlds + 18432 + (kf * 4 + nt) * 512 + lane * 8);
      const long a = pack64(av[0], av[1]);
      acc[0][nt] = __builtin_amdgcn_mfma_f32_32x32x16_fp8_fp8(a, bA, acc[0][nt], 0, 0, 0);
      acc[1][nt] = __builtin_amdgcn_mfma_f32_32x32x16_fp8_fp8(a, bB, acc[1][nt], 0, 0, 0);
    }
  }
  #pragma unroll
  for (int nt = 0; nt < 4; ++nt){   // bias block kf=8
    const u32x2 av = *reinterpret_cast<const u32x2*>(wlds + 18432 + (32 + nt) * 512 + lane * 8);
    const long a = pack64(av[0], av[1]);
    acc[0][nt] = __builtin_amdgcn_mfma_f32_32x32x16_fp8_fp8(a, bbias, acc[0][nt], 0, 0, 0);
    acc[1][nt] = __builtin_amdgcn_mfma_f32_32x32x16_fp8_fp8(a, bbias, acc[1][nt], 0, 0, 0);
  }
  __builtin_amdgcn_s_setprio(0);

  // ---- layer 3: relu + dot w3s (from LDS), lane<->lane+32 reduce, sigmoid
  #pragma unroll
  for (int gi = 0; gi < 2; ++gi){
    float pv = 0.f;
    #pragma unroll
    for (int nt = 0; nt < 4; ++nt)
      #pragma unroll
      for (int rq = 0; rq < 4; ++rq){
        const int cb = nt * 32 + rq * 8 + 4 * h;
        const float4 ww = *reinterpret_cast<const float4*>(wlds + WBYTES + cb * 4);
        pv += fmaxf(acc[gi][nt][rq*4+0], 0.f) * ww.x;
        pv += fmaxf(acc[gi][nt][rq*4+1], 0.f) * ww.y;
        pv += fmaxf(acc[gi][nt][rq*4+2], 0.f) * ww.z;
        pv += fmaxf(acc[gi][nt][rq*4+3], 0.f) * ww.w;
      }
    pv += __shfl_xor(pv, 32);
    const long g = g0 + gi;
    const bool v = gi ? v1 : v0;
    if (h == 0 && v){
      out[g * 32 + er] = 1.f / (1.f + expf(-(pv + bias3)));
    }
  }
}

// Block = 4 waves x 2 passes x 2 groups (16 groups, 512 edges).  36.5 KB LDS
// (W1+W2 fp8 K=144 frag-order + w3s), zero barriers after staging, 2 blocks/CU.
__global__ __launch_bounds__(256, 2) void mlp_main(
    const int* __restrict__ eidx,
    const unsigned char* __restrict__ nodef,
    const unsigned char* __restrict__ wblob,   // BLOB bytes
    const float* __restrict__ b3,
    float* __restrict__ out)
{
  __shared__ unsigned char wlds[BLOB];

  const int tid  = threadIdx.x;
  const int wave = tid >> 6;
  const int lane = tid & 63;
  const int er   = lane & 31;
  const int h    = lane >> 5;

  const long g0 = (long)blockIdx.x * GPB + wave * 2;
  const long g1 = g0 + 8;
  const bool p0v0 = (g0 < NG), p0v1 = (g0 + 1 < NG);
  const bool p1v0 = (g1 < NG), p1v1 = (g1 + 1 < NG);

  // ---- pass-0 idx + gathers FIRST (latency hides under W staging)
  u32x4 gA[4], gB[4];
  {
    const long ga = p0v0 ? g0 : 0;
    const long gb = p0v1 ? g0 + 1 : 0;
    const int isA = eidx[ga * 32 + er];
    const int idA = eidx[N_EDGESC + ga * 32 + er];
    const int isB = eidx[gb * 32 + er];
    const int idB = eidx[N_EDGESC + gb * 32 + er];
    gather_fp8(nodef, isA, idA, h, gA);
    gather_fp8(nodef, isB, idB, h, gB);
  }

  // ---- stage the 37376-B blob (lane-linear, conflict-free)
  #pragma unroll
  for (int j = 0; j < 10; ++j){
    const int c = j * 256 + tid;
    if (c < BLOB / 16)
      reinterpret_cast<int4*>(wlds)[c] = reinterpret_cast<const int4*>(wblob)[c];
  }
  __syncthreads();   // the only barrier

  const float bias3 = b3[0];

  do_pass<true >(wlds, lane, h, er, gA, gB, g0, p0v0, p0v1,
                 nodef, eidx, g1, bias3, out);
  do_pass<false>(wlds, lane, h, er, gA, gB, g1, p1v0, p1v1,
                 nodef, eidx, 0, bias3, out);
}

extern "C" void kernel_launch(void* const* d_in, const int* in_sizes, int n_in,
                              void* d_out, int out_size, void* d_ws, size_t ws_size,
                              hipStream_t stream){
  const float* node_rep = (const float*)d_in[0];
  const int*   eidx     = (const int*)d_in[1];
  const float* W1 = (const float*)d_in[2];
  const float* b1 = (const float*)d_in[3];
  const float* W2 = (const float*)d_in[4];
  const float* b2 = (const float*)d_in[5];
  const float* W3 = (const float*)d_in[6];
  const float* b3 = (const float*)d_in[7];
  float* out = (float*)d_out;

  unsigned* nodef = (unsigned*)d_ws;                              // 6.4 MB fp8
  unsigned char* wblob = (unsigned char*)d_ws + (size_t)N_NODES * NODE_DIM;
  unsigned short* wfp = (unsigned short*)wblob;
  float* w3s = (float*)(wblob + WBYTES);

  prep_kernel<<<2048 + 128, 256, 0, stream>>>(node_rep, W1, W2, b1, b2, W3,
                                              nodef, wfp, w3s);

  const int nblocks = (NG + GPB - 1) / GPB;   // 1954
  mlp_main<<<nblocks, 256, 0, stream>>>(eidx, (const unsigned char*)nodef,
                                        wblob, b3, out);
}

// Round 12
// 142.194 us; speedup vs baseline: 3.5864x; 1.0332x over previous
//
#include <hip/hip_runtime.h>
#include <math.h>

typedef float f32x16 __attribute__((ext_vector_type(16)));
typedef unsigned u32x4 __attribute__((ext_vector_type(4)));
typedef unsigned u32x2 __attribute__((ext_vector_type(2)));

#define N_NODES 100000
#define N_EDGESC 1000000
#define NODE_DIM 64
#define NG 31250            // 1e6 / 32 edges per group
#define GPB 8               // 4 waves x 1 group x 2 passes
#define WBYTES 36864        // 2 layers x 36 frags x 512 B
#define BLOB (WBYTES + 512) // + w3s (128 f32)

// pack 2 f32 -> fp8 e4m3 pair into lo or hi word
__device__ __forceinline__ unsigned pk2_lo(float a, float b){
#if __has_builtin(__builtin_amdgcn_cvt_pk_fp8_f32)
  return (unsigned)__builtin_amdgcn_cvt_pk_fp8_f32(a, b, 0, false);
#else
  unsigned r = 0;
  asm("v_cvt_pk_fp8_f32 %0, %1, %2" : "+v"(r) : "v"(a), "v"(b));
  return r;
#endif
}
__device__ __forceinline__ unsigned pk2_hi(float a, float b, unsigned old){
#if __has_builtin(__builtin_amdgcn_cvt_pk_fp8_f32)
  return (unsigned)__builtin_amdgcn_cvt_pk_fp8_f32(a, b, (int)old, true);
#else
  asm("v_cvt_pk_fp8_f32 %0, %1, %2 op_sel:[0,0,1]" : "+v"(old) : "v"(a), "v"(b));
  return old;
#endif
}
__device__ __forceinline__ unsigned pk4_fp8(float a, float b, float c, float d){
  return pk2_hi(c, d, pk2_lo(a, b));
}

__device__ __forceinline__ long pack64(unsigned lo, unsigned hi){
  return (long)(((unsigned long long)hi << 32) | lo);
}

// Prep (R11-verified): blocks [0,2048) cast node table f32 -> fp8 e4m3
// (6.4 MB, 64B rows = one cache line).  Blocks [2048,...): 37376-B weight blob:
//   bytes [0,18432):      W1 fp8 frag-order (x32), 9 kf-blocks (K=144).
//     kf<8: k-rows permuted for the contiguous gather:
//           feat = (kf>>2)*64 + h*32 + (kf&3)*8 + j
//     kf=8: bias block  A = (h==0 && j==0) ? 2*b1[n] : 0
//   bytes [18432,36864):  W2 fp8 frag-order (x32), plain k = kf*16+h*8+j,
//     kf=8: bias block  A = (h==0 && j==0) ? 64*b2[n] : 0
//   bytes [36864,37376):  w3s = w3 / 1024  (f32)
__global__ void prep_kernel(const float* __restrict__ node,
                            const float* __restrict__ w1,
                            const float* __restrict__ w2,
                            const float* __restrict__ b1,
                            const float* __restrict__ b2,
                            const float* __restrict__ w3,
                            unsigned* __restrict__ nodef,
                            unsigned short* __restrict__ wfp,
                            float* __restrict__ w3s){
  const int b = blockIdx.x;
  if (b < 2048){
    int i = b * 256 + threadIdx.x;
    const int n4 = N_NODES * NODE_DIM / 4;
    const int stride = 2048 * 256;
    for (; i < n4; i += stride){
      const float4 v = reinterpret_cast<const float4*>(node)[i];
      nodef[i] = pk4_fp8(v.x, v.y, v.z, v.w);
    }
  } else {
    const int i = (b - 2048) * 256 + threadIdx.x;
    if (i < 18432){
      const int bi = i * 2;
      const int layer = (bi >= 18432);
      const int off = bi - (layer ? 18432 : 0);
      const int f = off >> 9, rem = off & 511, l = rem >> 3, j0 = rem & 7;
      const int kf = f >> 2, nt = f & 3;
      const int h = l >> 5, n = nt * 32 + (l & 31);
      float v0, v1;
      if (kf < 8){
        if (!layer){
          const int feat = (kf >> 2) * 64 + h * 32 + (kf & 3) * 8 + j0;
          v0 = 32.0f * w1[feat * 128 + n];
          v1 = 32.0f * w1[(feat + 1) * 128 + n];
        } else {
          const int k = kf * 16 + h * 8 + j0;
          v0 = 32.0f * w2[k * 128 + n];
          v1 = 32.0f * w2[(k + 1) * 128 + n];
        }
      } else {
        v0 = (h == 0 && j0 == 0) ? (layer ? 64.0f * b2[n] : 2.0f * b1[n]) : 0.0f;
        v1 = 0.0f;
      }
      wfp[i] = (unsigned short)(pk2_lo(v0, v1) & 0xffffu);
    } else if (i < 18432 + 128){
      const int c = i - 18432;
      w3s[c] = w3[c] * 0.0009765625f;   // 1/1024
    }
  }
}

__device__ __forceinline__ void gather_fp8(const unsigned char* __restrict__ nodef,
                                           int is, int id, int h, u32x4 (&r)[4]){
  const unsigned char* s = nodef + (size_t)is * 64 + h * 32;
  const unsigned char* d = nodef + (size_t)id * 64 + h * 32;
  r[0] = *reinterpret_cast<const u32x4*>(s);
  r[1] = *reinterpret_cast<const u32x4*>(s + 16);
  r[2] = *reinterpret_cast<const u32x4*>(d);
  r[3] = *reinterpret_cast<const u32x4*>(d + 16);
}

// One pass over ONE 32-edge group (acc = 64 AGPR -> 3 waves/SIMD).
// All scales/biases in the MFMA K-dim (K=144, verified R11):
//   acc1 = 32*(feat.w1 + b1); h1s = fp8(relu(acc1)); acc2 = 1024*(h1.w2 + b2);
//   pv = sum fmax(acc2,0) * w3s  (w3s = w3/1024, LDS broadcast).
// If PF: next pass's idx at top, gather re-issued into the SAME buffer after L1.
template<bool PF>
__device__ __forceinline__ void do_pass(
    const unsigned char* wlds, int lane, int h, int er,
    u32x4 (&gr)[4], long g, bool valid,
    const unsigned char* __restrict__ nodef, const int* __restrict__ eidx,
    long gn, float bias3, float* __restrict__ out)
{
  int isn = 0, idn = 0;
  if (PF){
    const long gc = (gn < NG) ? gn : 0;
    isn = eidx[gc * 32 + er];
    idn = eidx[N_EDGESC + gc * 32 + er];
  }

  const long bbias = (h == 0) ? 0x58L : 0L;   // fp8 e4m3(16.0) byte0, h=0 lanes

  f32x16 acc[4];
  #pragma unroll
  for (int nt = 0; nt < 4; ++nt)
    #pragma unroll
    for (int q = 0; q < 16; ++q) acc[nt][q] = 0.f;

  // ---- layer 1 (fp8 x fp8): A = ds_read_b64, B from gather regs + bias block
  __builtin_amdgcn_s_setprio(1);
  #pragma unroll
  for (int kf = 0; kf < 8; ++kf){
    const int dw = (kf >> 2) * 8 + (kf & 3) * 2;
    const long bfr = pack64(gr[dw >> 2][dw & 3], gr[(dw + 1) >> 2][(dw + 1) & 3]);
    #pragma unroll
    for (int nt = 0; nt < 4; ++nt){
      const u32x2 av = *reinterpret_cast<const u32x2*>(wlds + (kf * 4 + nt) * 512 + lane * 8);
      acc[nt] = __builtin_amdgcn_mfma_f32_32x32x16_fp8_fp8(
          pack64(av[0], av[1]), bfr, acc[nt], 0, 0, 0);
    }
  }
  #pragma unroll
  for (int nt = 0; nt < 4; ++nt){   // bias block kf=8
    const u32x2 av = *reinterpret_cast<const u32x2*>(wlds + (32 + nt) * 512 + lane * 8);
    acc[nt] = __builtin_amdgcn_mfma_f32_32x32x16_fp8_fp8(
        pack64(av[0], av[1]), bbias, acc[nt], 0, 0, 0);
  }
  __builtin_amdgcn_s_setprio(0);

  // ---- gr dead: re-issue next pass's gather into the SAME buffer
  if (PF) gather_fp8(nodef, isn, idn, h, gr);

  // ---- relu + in-register crossover to fp8 B-frags (verified mapping)
  u32x2 b2f[8];
  #pragma unroll
  for (int nt = 0; nt < 4; ++nt){
    #pragma unroll
    for (int q = 0; q < 16; ++q) acc[nt][q] = fmaxf(acc[nt][q], 0.f);
    const unsigned u0 = pk4_fp8(acc[nt][0],  acc[nt][1],  acc[nt][2],  acc[nt][3]);
    const unsigned u1 = pk4_fp8(acc[nt][4],  acc[nt][5],  acc[nt][6],  acc[nt][7]);
    const unsigned u2 = pk4_fp8(acc[nt][8],  acc[nt][9],  acc[nt][10], acc[nt][11]);
    const unsigned u3 = pk4_fp8(acc[nt][12], acc[nt][13], acc[nt][14], acc[nt][15]);
    const unsigned s0 = h ? u0 : u1;
    const unsigned s1 = h ? u2 : u3;
    const unsigned t0 = (unsigned)__shfl_xor((int)s0, 32);
    const unsigned t1 = (unsigned)__shfl_xor((int)s1, 32);
    u32x2 f0, f1;
    f0[0] = h ? t0 : u0;  f0[1] = h ? u1 : t0;
    f1[0] = h ? t1 : u2;  f1[1] = h ? u3 : t1;
    b2f[2*nt]     = f0;
    b2f[2*nt + 1] = f1;
  }

  // ---- layer 2 (fp8 x fp8) + bias block
  #pragma unroll
  for (int nt = 0; nt < 4; ++nt)
    #pragma unroll
    for (int q = 0; q < 16; ++q) acc[nt][q] = 0.f;
  __builtin_amdgcn_s_setprio(1);
  #pragma unroll
  for (int kf = 0; kf < 8; ++kf){
    const long bfr = pack64(b2f[kf][0], b2f[kf][1]);
    #pragma unroll
    for (int nt = 0; nt < 4; ++nt){
      const u32x2 av = *reinterpret_cast<const u32x2*>(wlds + 18432 + (kf * 4 + nt) * 512 + lane * 8);
      acc[nt] = __builtin_amdgcn_mfma_f32_32x32x16_fp8_fp8(
          pack64(av[0], av[1]), bfr, acc[nt], 0, 0, 0);
    }
  }
  #pragma unroll
  for (int nt = 0; nt < 4; ++nt){   // bias block kf=8
    const u32x2 av = *reinterpret_cast<const u32x2*>(wlds + 18432 + (32 + nt) * 512 + lane * 8);
    acc[nt] = __builtin_amdgcn_mfma_f32_32x32x16_fp8_fp8(
        pack64(av[0], av[1]), bbias, acc[nt], 0, 0, 0);
  }
  __builtin_amdgcn_s_setprio(0);

  // ---- layer 3: relu + dot w3s (LDS broadcast), lane<->lane+32 reduce, sigmoid
  float pv = 0.f;
  #pragma unroll
  for (int nt = 0; nt < 4; ++nt)
    #pragma unroll
    for (int rq = 0; rq < 4; ++rq){
      const int cb = nt * 32 + rq * 8 + 4 * h;
      const float4 ww = *reinterpret_cast<const float4*>(wlds + WBYTES + cb * 4);
      pv += fmaxf(acc[nt][rq*4+0], 0.f) * ww.x;
      pv += fmaxf(acc[nt][rq*4+1], 0.f) * ww.y;
      pv += fmaxf(acc[nt][rq*4+2], 0.f) * ww.z;
      pv += fmaxf(acc[nt][rq*4+3], 0.f) * ww.w;
    }
  pv += __shfl_xor(pv, 32);
  if (h == 0 && valid){
    out[g * 32 + er] = 1.f / (1.f + expf(-(pv + bias3)));
  }
}

// Block = 4 waves x 2 passes x 1 group (8 groups, 256 edges).  36.5 KB LDS,
// zero barriers after staging, 3 blocks/CU (12 waves/CU) via small acc.
__global__ __launch_bounds__(256, 3) void mlp_main(
    const int* __restrict__ eidx,
    const unsigned char* __restrict__ nodef,
    const unsigned char* __restrict__ wblob,
    const float* __restrict__ b3,
    float* __restrict__ out)
{
  __shared__ unsigned char wlds[BLOB];

  const int tid  = threadIdx.x;
  const int wave = tid >> 6;
  const int lane = tid & 63;
  const int er   = lane & 31;
  const int h    = lane >> 5;

  const long g0 = (long)blockIdx.x * GPB + wave;       // pass 0
  const long g1 = g0 + 4;                              // pass 1
  const bool v0 = (g0 < NG), v1 = (g1 < NG);

  // ---- pass-0 idx + gather FIRST (latency hides under W staging)
  u32x4 gr[4];
  {
    const long gc = v0 ? g0 : 0;
    const int is = eidx[gc * 32 + er];
    const int id = eidx[N_EDGESC + gc * 32 + er];
    gather_fp8(nodef, is, id, h, gr);
  }

  // ---- stage the 37376-B blob (lane-linear, conflict-free)
  #pragma unroll
  for (int j = 0; j < 10; ++j){
    const int c = j * 256 + tid;
    if (c < BLOB / 16)
      reinterpret_cast<int4*>(wlds)[c] = reinterpret_cast<const int4*>(wblob)[c];
  }
  __syncthreads();   // the only barrier

  const float bias3 = b3[0];

  do_pass<true >(wlds, lane, h, er, gr, g0, v0, nodef, eidx, g1, bias3, out);
  do_pass<false>(wlds, lane, h, er, gr, g1, v1, nodef, eidx, 0,  bias3, out);
}

extern "C" void kernel_launch(void* const* d_in, const int* in_sizes, int n_in,
                              void* d_out, int out_size, void* d_ws, size_t ws_size,
                              hipStream_t stream){
  const float* node_rep = (const float*)d_in[0];
  const int*   eidx     = (const int*)d_in[1];
  const float* W1 = (const float*)d_in[2];
  const float* b1 = (const float*)d_in[3];
  const float* W2 = (const float*)d_in[4];
  const float* b2 = (const float*)d_in[5];
  const float* W3 = (const float*)d_in[6];
  const float* b3 = (const float*)d_in[7];
  float* out = (float*)d_out;

  unsigned* nodef = (unsigned*)d_ws;                              // 6.4 MB fp8
  unsigned char* wblob = (unsigned char*)d_ws + (size_t)N_NODES * NODE_DIM;
  unsigned short* wfp = (unsigned short*)wblob;
  float* w3s = (float*)(wblob + WBYTES);

  prep_kernel<<<2048 + 128, 256, 0, stream>>>(node_rep, W1, W2, b1, b2, W3,
                                              nodef, wfp, w3s);

  const int nblocks = (NG + GPB - 1) / GPB;   // 3907
  mlp_main<<<nblocks, 256, 0, stream>>>(eidx, (const unsigned char*)nodef,
                                        wblob, b3, out);
}